// Round 1
// baseline (95.229 us; speedup 1.0000x reference)
//
#include <hip/hip_runtime.h>
#include <hip/hip_bf16.h>

#define B_ROWS 4096
#define N_ROWS 8192
#define D 128
#define INV_T 2.0f            // 1 / temperature(0.5)

#define RB 128                // rows per workgroup (main kernel)
#define CS_COLS 1024          // columns per col-split
#define CHUNK 64              // columns staged per LDS pass
#define LDS_STRIDE 136        // 128 + 8 bf16 pad -> 272 B row stride (breaks bank conflicts, keeps 16B align)

typedef __attribute__((ext_vector_type(8))) short bf16x8;
typedef __attribute__((ext_vector_type(4))) float f32x4;

__device__ inline unsigned short f32_to_bf16_rne(float f) {
    unsigned int u = __float_as_uint(f);
    u += 0x7fffu + ((u >> 16) & 1u);   // round-to-nearest-even (no NaN inputs here)
    return (unsigned short)(u >> 16);
}
__device__ inline float bf16s_to_f32(short s) {
    unsigned int u = ((unsigned int)(unsigned short)s) << 16;
    return __uint_as_float(u);
}

// ---------------- Kernel 1: row-normalize fp32 -> bf16 ----------------
// grid = N_ROWS blocks of 64 threads; one wave per row, float2 per lane.
__global__ void k_normalize(const float* __restrict__ z_i,
                            const float* __restrict__ z_j,
                            unsigned short* __restrict__ zn) {
    int row  = blockIdx.x;
    int lane = threadIdx.x;
    const float* src = (row < B_ROWS) ? (z_i + (size_t)row * D)
                                      : (z_j + (size_t)(row - B_ROWS) * D);
    float2 v = ((const float2*)src)[lane];
    float ss = v.x * v.x + v.y * v.y;
    #pragma unroll
    for (int m = 1; m < 64; m <<= 1) ss += __shfl_xor(ss, m);
    float rinv = 1.0f / fmaxf(sqrtf(ss), 1e-8f);
    ushort2 o;
    o.x = f32_to_bf16_rne(v.x * rinv);
    o.y = f32_to_bf16_rne(v.y * rinv);
    ((ushort2*)(zn + (size_t)row * D))[lane] = o;
}

// ---------------- Kernel 2: fused sim-GEMM + exp + row-sum ----------------
// grid = (N_ROWS/RB, N_ROWS/CS_COLS) = (64, 8), block = 256 (4 waves).
// Wave w owns rows blockIdx.x*128 + w*32 .. +32 (two 16-row MFMA tiles).
// For C = Zn * Zn^T both A and B fragments use the identical per-lane layout
// frag[j] = zn[tile_base + (lane&15)][kb*32 + (lane>>4)*8 + j].
__global__ __launch_bounds__(256)
void k_simsum(const unsigned short* __restrict__ zn,
              float* __restrict__ denom) {
    __shared__ unsigned short sB[CHUNK * LDS_STRIDE];
    const int tid  = threadIdx.x;
    const int wave = tid >> 6;
    const int lane = tid & 63;
    const int l15  = lane & 15;
    const int quad = lane >> 4;
    const int m0   = blockIdx.x * RB + wave * 32;

    // A fragments: 2 row-tiles x 4 k-blocks, kept in registers for the whole sweep
    bf16x8 A[2][4];
    #pragma unroll
    for (int rt = 0; rt < 2; ++rt)
        #pragma unroll
        for (int kb = 0; kb < 4; ++kb)
            A[rt][kb] = *(const bf16x8*)(zn + (size_t)(m0 + rt * 16 + l15) * D + kb * 32 + quad * 8);

    float rs[2][4] = {{0.f,0.f,0.f,0.f},{0.f,0.f,0.f,0.f}};
    const int c_base = blockIdx.y * CS_COLS;

    for (int cb = 0; cb < CS_COLS / CHUNK; ++cb) {
        __syncthreads();                       // previous iteration's LDS reads done
        const int c0 = c_base + cb * CHUNK;
        // stage 64 zn rows (16 KB) -> LDS, 4 x 16B per thread, fully coalesced
        #pragma unroll
        for (int p = 0; p < 4; ++p) {
            int i  = tid + p * 256;
            int r  = i >> 4;
            int cc = i & 15;
            *(bf16x8*)(sB + r * LDS_STRIDE + cc * 8) =
                *(const bf16x8*)(zn + (size_t)(c0 + r) * D + cc * 8);
        }
        __syncthreads();

        #pragma unroll
        for (int t = 0; t < 4; ++t) {          // 4 col-tiles of 16 per chunk
            bf16x8 b[4];
            #pragma unroll
            for (int kb = 0; kb < 4; ++kb)
                b[kb] = *(const bf16x8*)(sB + (t * 16 + l15) * LDS_STRIDE + kb * 32 + quad * 8);
            f32x4 acc0 = {0.f,0.f,0.f,0.f};
            f32x4 acc1 = {0.f,0.f,0.f,0.f};
            #pragma unroll
            for (int kb = 0; kb < 4; ++kb) {
                acc0 = __builtin_amdgcn_mfma_f32_16x16x32_bf16(A[0][kb], b[kb], acc0, 0, 0, 0);
                acc1 = __builtin_amdgcn_mfma_f32_16x16x32_bf16(A[1][kb], b[kb], acc1, 0, 0, 0);
            }
            #pragma unroll
            for (int j = 0; j < 4; ++j) {
                rs[0][j] += __expf(acc0[j] * INV_T);
                rs[1][j] += __expf(acc1[j] * INV_T);
            }
        }
    }

    // rs[rt][j] holds partial sum for row m0+rt*16+quad*4+j over cols == l15 (mod 16);
    // reduce across the 16 column lanes of each quad.
    #pragma unroll
    for (int rt = 0; rt < 2; ++rt)
        #pragma unroll
        for (int j = 0; j < 4; ++j) {
            float v = rs[rt][j];
            v += __shfl_xor(v, 1);
            v += __shfl_xor(v, 2);
            v += __shfl_xor(v, 4);
            v += __shfl_xor(v, 8);
            rs[rt][j] = v;
        }
    if (l15 == 0) {
        #pragma unroll
        for (int rt = 0; rt < 2; ++rt)
            #pragma unroll
            for (int j = 0; j < 4; ++j)
                atomicAdd(&denom[m0 + rt * 16 + quad * 4 + j], rs[rt][j]);
    }
}

// ---------------- Kernel 3: per-row loss + mean reduce ----------------
// grid = N_ROWS/256 blocks; thread = one row.
__global__ void k_finalize(const unsigned short* __restrict__ zn,
                           const float* __restrict__ denom,
                           float* __restrict__ out) {
    int i = blockIdx.x * blockDim.x + threadIdx.x;
    int p = (i + B_ROWS) & (N_ROWS - 1);
    const unsigned short* zi = zn + (size_t)i * D;
    const unsigned short* zp = zn + (size_t)p * D;
    float self_dot = 0.f, pos_dot = 0.f;
    #pragma unroll
    for (int c = 0; c < D / 8; ++c) {
        bf16x8 a = *(const bf16x8*)(zi + c * 8);
        bf16x8 b = *(const bf16x8*)(zp + c * 8);
        #pragma unroll
        for (int j = 0; j < 8; ++j) {
            float av = bf16s_to_f32(a[j]);
            float bv = bf16s_to_f32(b[j]);
            self_dot += av * av;
            pos_dot  += av * bv;
        }
    }
    // denom row-sum included self and pos; subtract self term (same bf16 arithmetic).
    float dnm  = denom[i] - __expf(self_dot * INV_T);
    float loss = __logf(dnm) - pos_dot * INV_T;   // -log(pos/denom), log(exp(s)) = s

    // block reduction
    float v = loss;
    #pragma unroll
    for (int m = 1; m < 64; m <<= 1) v += __shfl_xor(v, m);
    __shared__ float ws[4];
    int wave = threadIdx.x >> 6;
    if ((threadIdx.x & 63) == 0) ws[wave] = v;
    __syncthreads();
    if (threadIdx.x == 0) {
        float s = ws[0] + ws[1] + ws[2] + ws[3];
        atomicAdd(out, s * (1.0f / (float)N_ROWS));
    }
}

extern "C" void kernel_launch(void* const* d_in, const int* in_sizes, int n_in,
                              void* d_out, int out_size, void* d_ws, size_t ws_size,
                              hipStream_t stream) {
    const float* z_i = (const float*)d_in[0];
    const float* z_j = (const float*)d_in[1];
    float* out = (float*)d_out;

    unsigned short* zn = (unsigned short*)d_ws;                      // N*D bf16 = 2 MB
    float* denom = (float*)((char*)d_ws + (size_t)N_ROWS * D * 2);   // N fp32 = 32 KB

    hipMemsetAsync(denom, 0, N_ROWS * sizeof(float), stream);
    hipMemsetAsync(out, 0, sizeof(float), stream);

    k_normalize<<<N_ROWS, 64, 0, stream>>>(z_i, z_j, zn);
    k_simsum<<<dim3(N_ROWS / RB, N_ROWS / CS_COLS), 256, 0, stream>>>(zn, denom);
    k_finalize<<<N_ROWS / 256, 256, 0, stream>>>(zn, denom, out);
}